// Round 1
// 169.948 us; speedup vs baseline: 1.0140x; 1.0140x over previous
//
#include <hip/hip_runtime.h>
#include <math.h>

namespace {
constexpr int B    = 4;
constexpr int N    = 8192;
constexpr int P    = 2048;
constexpr int C    = 128;
constexpr int COUT = 256;
constexpr int NS   = 32;
constexpr int BP   = B * P;     // 8192
constexpr int BPB  = 2;         // bp per group (4 m-tiles -> acc[4][4] = 64 VGPRs)
constexpr int GRP  = 8;         // groups per block
constexpr int NBLK = BP / (BPB * GRP); // 512 blocks (2/CU)

// ---- workspace layout (bytes, all 256-aligned) ----
constexpr size_t OFF_FEATT = 0;                          // B*N*C bf16    = 8388608
constexpr size_t OFF_WSWZ  = 8388608;                    // 40960 bf16    = 81920
constexpr size_t OFF_NXD   = 8470528;                    // 8192*3 f64    = 196608
constexpr size_t OFF_NXF   = 8667136;                    // 8192*3 f32    = 98304
constexpr size_t OFF_IDX   = 8765440;                    // 8192*32 i32   = 1048576
constexpr size_t OFF_YMAX  = 9814016;                    // 8192*256 f32  = 8388608
constexpr size_t OFF_PART  = 18202624;                   // 512*512 f32   = 1048576
constexpr size_t OFF_P2    = 19251200;                   // 128*512 f32   = 262144
constexpr size_t OFF_AB    = 19513344;                   // 512 f32       = 2048
constexpr size_t WS_NEED   = 19515392;                   // ~18.6 MB
} // namespace

typedef short bf16x8 __attribute__((ext_vector_type(8)));
typedef float f32x4  __attribute__((ext_vector_type(4)));

typedef const __attribute__((address_space(1))) void gas_void;
typedef __attribute__((address_space(3))) void las_void;
#define GLOBAL_LOAD_LDS16(gp, lp) \
    __builtin_amdgcn_global_load_lds((gas_void*)(gp), (las_void*)(lp), 16, 0, 0)

__device__ inline unsigned short f2bf(float f) {
    unsigned u = __float_as_uint(f);
    unsigned r = u + 0x7fffu + ((u >> 16) & 1u);
    return (unsigned short)(r >> 16);
}

// ---------------- K0a: transpose features (B,C,N) f32 -> (B,N,C) bf16 ----------------
// R6: write phase now emits one 16B store per thread (was 4x 4B).
__global__ __launch_bounds__(256) void k_transpose(const float* __restrict__ feat,
                                                   unsigned short* __restrict__ featT) {
    __shared__ float tile[64][33];
    int tx = threadIdx.x, ty = threadIdx.y;        // 32 x 8
    int n0 = blockIdx.x * 32, c0 = blockIdx.y * 64, b = blockIdx.z;
    const float* src = feat + ((size_t)b * C + c0) * N + n0;
#pragma unroll
    for (int j = 0; j < 8; j++) tile[ty + 8 * j][tx] = src[(size_t)(ty + 8 * j) * N + tx];
    __syncthreads();
    int t = ty * 32 + tx;                          // 0..255
    int n = t >> 3;                                // 0..31
    int k8 = (t & 7) * 8;                          // cout sub-offset 0..56
    unsigned vv[4];
#pragma unroll
    for (int i = 0; i < 4; i++) {
        unsigned lo = f2bf(tile[k8 + 2 * i][n]);
        unsigned hi = f2bf(tile[k8 + 2 * i + 1][n]);
        vv[i] = lo | (hi << 16);
    }
    *(int4*)&featT[((size_t)b * N + n0 + n) * C + c0 + k8] =
        make_int4((int)vv[0], (int)vv[1], (int)vv[2], (int)vv[3]);
}

// ---------------- K0b: swizzle w_mlp into MFMA fragment order (bf16) ----------------
// wswz[rt(16)][ks(5)][lane(64)][j(8)]; element = W[rt*16+(lane&15)][k'] with
// k' = ks*32+(lane>>4)*8+j; k-map: 0..127 -> w col 3+k' (feats); 128..130 -> w col
// 0..2 (xyz); else 0. Used as B-fragment (n=cout); A/B fragment index maps coincide.
__global__ __launch_bounds__(256) void k_wswz(const float* __restrict__ w,
                                              unsigned short* __restrict__ wswz) {
    int i = blockIdx.x * 256 + threadIdx.x;        // < 40960
    int j = i & 7;
    int lane = (i >> 3) & 63;
    int rest = i >> 9;                             // 0..79
    int ks = rest % 5, rt = rest / 5;
    int cout = rt * 16 + (lane & 15);
    int k = ks * 32 + (lane >> 4) * 8 + j;
    float v = 0.f;
    if (k < 128) v = w[cout * 131 + 3 + k];
    else if (k < 131) v = w[cout * 131 + (k - 128)];
    wswz[i] = f2bf(v);
}

// ---------------- K1: shift conv + BN(train) + ReLU, fp64 to match np ref ----------------
__global__ __launch_bounds__(1024) void k_shift(const float* __restrict__ ffps,
                                                const float* __restrict__ wsh,
                                                const float* __restrict__ gam,
                                                const float* __restrict__ bet,
                                                double* __restrict__ nxd,
                                                float* __restrict__ nxf) {
#pragma clang fp contract(off)
    __shared__ double red[6][1024];
    __shared__ double par[6];
    int t = threadIdx.x;
    double w[9];
#pragma unroll
    for (int i = 0; i < 9; i++) w[i] = (double)wsh[i];
    double x[8][3];
    double s[3] = {0, 0, 0}, sq[3] = {0, 0, 0};
#pragma unroll
    for (int i = 0; i < 8; i++) {
        int p = t + 1024 * i;
        double f0 = (double)ffps[p * 3 + 0];
        double f1 = (double)ffps[p * 3 + 1];
        double f2 = (double)ffps[p * 3 + 2];
#pragma unroll
        for (int o = 0; o < 3; o++) {
            double xo = (w[o * 3 + 0] * f0 + w[o * 3 + 1] * f1) + w[o * 3 + 2] * f2;
            x[i][o] = xo;
            s[o] += xo;
            sq[o] += xo * xo;
        }
    }
#pragma unroll
    for (int o = 0; o < 3; o++) { red[o][t] = s[o]; red[3 + o][t] = sq[o]; }
    for (int off = 512; off > 0; off >>= 1) {
        __syncthreads();
        if (t < off) {
#pragma unroll
            for (int j = 0; j < 6; j++) red[j][t] += red[j][t + off];
        }
    }
    __syncthreads();
    if (t == 0) {
#pragma unroll
        for (int o = 0; o < 3; o++) {
            double m = red[o][0] / (double)BP;
            double v = red[3 + o][0] / (double)BP - m * m;
            par[o] = m;
            par[3 + o] = 1.0 / sqrt(v + 1e-5);
        }
    }
    __syncthreads();
    double gv[3] = {(double)gam[0], (double)gam[1], (double)gam[2]};
    double bv[3] = {(double)bet[0], (double)bet[1], (double)bet[2]};
#pragma unroll
    for (int i = 0; i < 8; i++) {
        int p = t + 1024 * i;
#pragma unroll
        for (int o = 0; o < 3; o++) {
            double y = ((x[i][o] - par[o]) * par[3 + o]) * gv[o] + bv[o];
            y = (y > 0.0) ? y : 0.0;
            nxd[p * 3 + o] = y;
            nxf[p * 3 + o] = (float)y;
        }
    }
}

// ---------------- K2: ball query, 512-pt iterations + depth-2 pipeline ----------------
// R6: depth-1 prefetch (R5 fix) only covers ~250cyc of ~300-1100cyc gather latency;
// worst-case scan waves still stalled every 256-pt iteration. Now: 8 chunks (512
// pts)/iteration with THREE register buffers and a 3-phase unrolled loop (rotation
// baked into phase roles -> no copies, no runtime-indexed arrays). Load for it+3
// issued right after processing it -> ~2 full iterations (~800cyc) in flight.
// Scan order / ballot rank / padding semantics identical to before.
__global__ __launch_bounds__(256) void k_ballq(const float* __restrict__ bbxyz,
                                               const double* __restrict__ nxd,
                                               int* __restrict__ idxo) {
#pragma clang fp contract(off)
    int t = threadIdx.x;
    int wv = t >> 6, lane = t & 63;
    int q = blockIdx.x * 4 + wv;                   // bp index
    int b = q >> 11;                               // P = 2048
    double qx = nxd[q * 3 + 0], qy = nxd[q * 3 + 1], qz = nxd[q * 3 + 2];
    const double R2 = 0.8 * 0.8;
    // early-out: ball cannot intersect backbone cube [-1,1]^3 -> zero neighbors,
    // reference pads with index 0 in that case.
    {
        double ex = fmax(fmax(qx - 1.0, -1.0 - qx), 0.0);
        double ey = fmax(fmax(qy - 1.0, -1.0 - qy), 0.0);
        double ez = fmax(fmax(qz - 1.0, -1.0 - qz), 0.0);
        if (ex * ex + ey * ey + ez * ez >= R2) {
            if (lane < NS) idxo[q * NS + lane] = 0;
            return;
        }
    }
    const float* base = bbxyz + (size_t)b * N * 3;
    int found = 0, firstn = -1;

    float X0[8], Y0[8], Z0[8], X1[8], Y1[8], Z1[8], X2[8], Y2[8], Z2[8];

    auto loadb = [&](float (&XX)[8], float (&YY)[8], float (&ZZ)[8], int it) {
#pragma unroll
        for (int j = 0; j < 8; j++) {
            int n = it * 512 + j * 64 + lane;
            XX[j] = base[n * 3 + 0];
            YY[j] = base[n * 3 + 1];
            ZZ[j] = base[n * 3 + 2];
        }
    };
    auto proc = [&](float (&XX)[8], float (&YY)[8], float (&ZZ)[8], int it) {
#pragma clang fp contract(off)
#pragma unroll
        for (int j = 0; j < 8; j++) {
            int n = it * 512 + j * 64 + lane;
            double dx = qx - (double)XX[j];
            double dy = qy - (double)YY[j];
            double dz = qz - (double)ZZ[j];
            double d2 = (dx * dx + dy * dy) + dz * dz;
            bool within = d2 < R2;
            unsigned long long mask = __ballot(within);
            if (firstn < 0 && mask != 0ull) firstn = (n - lane) + (__ffsll(mask) - 1);
            if (within) {
                int rank = found + __popcll(mask & ((1ull << lane) - 1ull));
                if (rank < NS) idxo[q * NS + rank] = n;
            }
            found += __popcll(mask);
        }
    };

    loadb(X0, Y0, Z0, 0);
    loadb(X1, Y1, Z1, 1);
    loadb(X2, Y2, Z2, 2);

    for (int itb = 0; itb < 16; itb += 3) {        // iterations of 512 pts; N/512 = 16
        proc(X0, Y0, Z0, itb);
        if (found >= NS) break;
        loadb(X0, Y0, Z0, (itb + 3 < 16) ? itb + 3 : 0);
        if (itb + 1 >= 16) break;
        proc(X1, Y1, Z1, itb + 1);
        if (found >= NS) break;
        loadb(X1, Y1, Z1, (itb + 4 < 16) ? itb + 4 : 0);
        if (itb + 2 >= 16) break;
        proc(X2, Y2, Z2, itb + 2);
        if (found >= NS) break;
        loadb(X2, Y2, Z2, (itb + 5 < 16) ? itb + 5 : 0);
    }
    if (found < NS) {
        int padv = (found == 0) ? 0 : firstn;
        if (lane >= found && lane < NS) idxo[q * NS + lane] = padv;
    }
}

// ---------------- K3: MFMA grouped 1x1 conv, pipelined, register-budgeted ----------
// 512 blocks x 8 groups x 2 bp. A = G (m=samples), B = W^T (n=couts). W fragments
// (wreg[5][4], 80 VGPRs) loaded ONCE and live across all groups; acc[4][4] = 64
// VGPRs; total deliberate ~210 < 256 (launch_bounds(256,2)) -> no spill. Feats
// double-buffered via global_load_lds(16B); each wave stages m-tile mt==w.
// xyz enters as in-register ks=4 A-frag. R6: idx prefetch deepened to 2 groups
// (n_nx2) so the scattered idx gather latency is covered by a full group of
// compute instead of only the barrier window.
__global__ __launch_bounds__(256, 2) void k_mlp_mfma(
        const float* __restrict__ bbxyz,
        const unsigned short* __restrict__ featT,
        const unsigned short* __restrict__ wswz,
        const float* __restrict__ nxf,
        const int* __restrict__ idx,
        float* __restrict__ ymax,
        float* __restrict__ partial) {
    // G[buf][(mt*4+ks)*64 + lane][8]: element (s = mt*16+(lane&15), k' = ks*32+(lane>>4)*8+j)
    __shared__ alignas(16) unsigned short G[2][4 * 4 * 64 * 8];   // 2 x 16384 B
    int t = threadIdx.x, lane = t & 63, w = t >> 6;
    int q = lane >> 4, c16 = lane & 15;
    int blk = blockIdx.x;
    int bpbase = blk * (BPB * GRP);                // 16 bp per block
    const bf16x8* wp = (const bf16x8*)wswz;

    // ---- W fragments resident in registers for the whole kernel ----
    bf16x8 wreg[5][4];
#pragma unroll
    for (int ks = 0; ks < 5; ks++)
#pragma unroll
        for (int nt = 0; nt < 4; nt++)
            wreg[ks][nt] = wp[((w * 4 + nt) * 5 + ks) * 64 + lane];

    int n_cur[4], n_nxt[4], n_nx2[4];
#pragma unroll
    for (int mt = 0; mt < 4; mt++)
        n_cur[mt] = idx[(bpbase + (mt >> 1)) * NS + (mt & 1) * 16 + c16];
#pragma unroll
    for (int mt = 0; mt < 4; mt++)
        n_nxt[mt] = idx[(bpbase + BPB + (mt >> 1)) * NS + (mt & 1) * 16 + c16];
    {   // stage group 0: wave w stages m-tile w
        int bp = bpbase + (w >> 1);
        const unsigned short* row = featT + ((size_t)(bp >> 11) * N + n_cur[w]) * C + q * 8;
#pragma unroll
        for (int ks = 0; ks < 4; ks++)
            GLOBAL_LOAD_LDS16(row + ks * 32, &G[0][(w * 4 + ks) * 512]);
    }

    float smA[4] = {0.f, 0.f, 0.f, 0.f}, sqA[4] = {0.f, 0.f, 0.f, 0.f};

    for (int g = 0; g < GRP; g++) {
        int buf = g & 1;
        int bp0 = bpbase + g * BPB;
        if (g + 2 < GRP) {
#pragma unroll
            for (int mt = 0; mt < 4; mt++)
                n_nx2[mt] = idx[(bp0 + 2 * BPB + (mt >> 1)) * NS + (mt & 1) * 16 + c16];
        }
        __syncthreads();   // stage(g) drained; compute(g-1) reads of buf^1 done
        if (g + 1 < GRP) {
            int bp = bp0 + BPB + (w >> 1);
            const unsigned short* row = featT + ((size_t)(bp >> 11) * N + n_nxt[w]) * C + q * 8;
#pragma unroll
            for (int ks = 0; ks < 4; ks++)
                GLOBAL_LOAD_LDS16(row + ks * 32, &G[buf ^ 1][(w * 4 + ks) * 512]);
        }

        // ---- compute(g) on G[buf] ----
        f32x4 acc[4][4];
#pragma unroll
        for (int mt = 0; mt < 4; mt++)
#pragma unroll
            for (int nt = 0; nt < 4; nt++) acc[mt][nt] = (f32x4){0.f, 0.f, 0.f, 0.f};

#pragma unroll
        for (int ks = 0; ks < 4; ks++) {
            bf16x8 ag[4];
#pragma unroll
            for (int mt = 0; mt < 4; mt++)
                ag[mt] = *(const bf16x8*)&G[buf][((mt * 4 + ks) * 64 + lane) * 8];
#pragma unroll
            for (int nt = 0; nt < 4; nt++)
#pragma unroll
                for (int mt = 0; mt < 4; mt++)
                    acc[mt][nt] = __builtin_amdgcn_mfma_f32_16x16x32_bf16(ag[mt], wreg[ks][nt], acc[mt][nt], 0, 0, 0);
        }
        {   // ks = 4: xyz A-frags in registers (q==0: j0..2 = recentered xyz, else 0)
            bf16x8 agx[4];
#pragma unroll
            for (int mt = 0; mt < 4; mt++) {
                int bp = bp0 + (mt >> 1);
                unsigned u01 = 0, u23 = 0;
                if (q == 0) {
                    const float* src = bbxyz + ((size_t)(bp >> 11) * N + n_cur[mt]) * 3;
                    const float* ctr = nxf + bp * 3;
                    u01 = (unsigned)f2bf(src[0] - ctr[0]) | ((unsigned)f2bf(src[1] - ctr[1]) << 16);
                    u23 = (unsigned)f2bf(src[2] - ctr[2]);
                }
                union { int4 i; bf16x8 h; } u;
                u.i = make_int4((int)u01, (int)u23, 0, 0);
                agx[mt] = u.h;
            }
#pragma unroll
            for (int nt = 0; nt < 4; nt++)
#pragma unroll
                for (int mt = 0; mt < 4; mt++)
                    acc[mt][nt] = __builtin_amdgcn_mfma_f32_16x16x32_bf16(agx[mt], wreg[4][nt], acc[mt][nt], 0, 0, 0);
        }

        // ---- epilogue: max over 32 samples (2 m-tiles) per bp; sums accumulate ----
#pragma unroll
        for (int pm = 0; pm < BPB; pm++) {
            int bp = bp0 + pm;
#pragma unroll
            for (int nt = 0; nt < 4; nt++) {
                f32x4 a = acc[2 * pm][nt], c = acc[2 * pm + 1][nt];
                float mx = fmaxf(fmaxf(fmaxf(a[0], a[1]), fmaxf(a[2], a[3])),
                                 fmaxf(fmaxf(c[0], c[1]), fmaxf(c[2], c[3])));
                smA[nt] += ((a[0] + a[1]) + (a[2] + a[3])) + ((c[0] + c[1]) + (c[2] + c[3]));
                sqA[nt] += ((a[0] * a[0] + a[1] * a[1]) + (a[2] * a[2] + a[3] * a[3])) +
                           ((c[0] * c[0] + c[1] * c[1]) + (c[2] * c[2] + c[3] * c[3]));
                mx = fmaxf(mx, __shfl_xor(mx, 16, 64));
                mx = fmaxf(mx, __shfl_xor(mx, 32, 64));
                if (q == 0)
                    ymax[(size_t)bp * COUT + w * 64 + nt * 16 + c16] = mx;
            }
        }
#pragma unroll
        for (int mt = 0; mt < 4; mt++) { n_cur[mt] = n_nxt[mt]; n_nxt[mt] = n_nx2[mt]; }
    }

    // ---- block-level sum butterfly (once) ----
#pragma unroll
    for (int nt = 0; nt < 4; nt++) {
        float sm = smA[nt], sq = sqA[nt];
        sm += __shfl_xor(sm, 16, 64);
        sm += __shfl_xor(sm, 32, 64);
        sq += __shfl_xor(sq, 16, 64);
        sq += __shfl_xor(sq, 32, 64);
        if (q == 0) {
            int cout = w * 64 + nt * 16 + c16;
            partial[(size_t)blk * 512 + cout] = sm;
            partial[(size_t)blk * 512 + 256 + cout] = sq;
        }
    }
}

// ---------------- K4a: reduce partial (512x512) -> (128x512) ----------------
__global__ __launch_bounds__(256) void k_red(const float* __restrict__ partial,
                                             float* __restrict__ p2) {
    int t = threadIdx.x, j = blockIdx.x;
    const float* row = partial + (size_t)j * 4 * 512;
    float s0 = 0.f, s1 = 0.f;
    for (int r = 0; r < 4; r++) {
        s0 += row[r * 512 + t];
        s1 += row[r * 512 + 256 + t];
    }
    p2[j * 512 + t] = s0;
    p2[j * 512 + 256 + t] = s1;
}

// ---------------- K4b: final stats -> per-channel scale/bias ----------------
__global__ __launch_bounds__(256) void k_stats(const float* __restrict__ p2,
                                               const float* __restrict__ gam,
                                               const float* __restrict__ bet,
                                               float* __restrict__ ab) {
    int c = threadIdx.x;
    double sm = 0.0, sq = 0.0;
    for (int r = 0; r < 128; r++) {
        sm += (double)p2[r * 512 + c];
        sq += (double)p2[r * 512 + 256 + c];
    }
    const double cnt = (double)BP * (double)NS;    // 262144
    double mean = sm / cnt;
    double var = sq / cnt - mean * mean;
    double a = (double)gam[c] / sqrt(var + 1e-5);  // gamma==1 -> a>0 always
    double bb = (double)bet[c] - mean * a;
    ab[c] = (float)a;
    ab[256 + c] = (float)bb;
}

// ---------------- K5: out = relu(a * ymax + b), float4 ----------------
__global__ __launch_bounds__(256) void k_final(const float* __restrict__ ymax,
                                               const float* __restrict__ ab,
                                               float* __restrict__ out) {
    int i = blockIdx.x * 256 + threadIdx.x;        // float4 index, < BP*COUT/4
    int c0 = (i & 63) * 4;
    f32x4 y = *(const f32x4*)&ymax[(size_t)i * 4];
    f32x4 a = *(const f32x4*)&ab[c0];
    f32x4 bb = *(const f32x4*)&ab[256 + c0];
    f32x4 r;
#pragma unroll
    for (int j = 0; j < 4; j++) r[j] = fmaxf(a[j] * y[j] + bb[j], 0.f);
    *(f32x4*)&out[(size_t)i * 4] = r;
}

extern "C" void kernel_launch(void* const* d_in, const int* in_sizes, int n_in,
                              void* d_out, int out_size, void* d_ws, size_t ws_size,
                              hipStream_t stream) {
    const float* ffps  = (const float*)d_in[0];
    const float* bbxyz = (const float*)d_in[1];
    const float* feat  = (const float*)d_in[2];
    const float* wsh   = (const float*)d_in[3];
    const float* gsh   = (const float*)d_in[4];
    const float* bsh   = (const float*)d_in[5];
    const float* wml   = (const float*)d_in[6];
    const float* gml   = (const float*)d_in[7];
    const float* bml   = (const float*)d_in[8];
    float* out = (float*)d_out;
    char* ws = (char*)d_ws;
    if (ws_size < WS_NEED) return;

    unsigned short* featT = (unsigned short*)(ws + OFF_FEATT);
    unsigned short* wswz  = (unsigned short*)(ws + OFF_WSWZ);
    double*         nxd   = (double*)(ws + OFF_NXD);
    float*          nxf   = (float*)(ws + OFF_NXF);
    int*            idx   = (int*)(ws + OFF_IDX);
    float*          ymax  = (float*)(ws + OFF_YMAX);
    float*          part  = (float*)(ws + OFF_PART);
    float*          p2    = (float*)(ws + OFF_P2);
    float*          ab    = (float*)(ws + OFF_AB);

    k_transpose<<<dim3(N / 32, C / 64, B), dim3(32, 8, 1), 0, stream>>>(feat, featT);
    k_wswz<<<dim3(160), dim3(256), 0, stream>>>(wml, wswz);
    k_shift<<<dim3(1), dim3(1024), 0, stream>>>(ffps, wsh, gsh, bsh, nxd, nxf);
    k_ballq<<<dim3(BP / 4), dim3(256), 0, stream>>>(bbxyz, nxd, idx);
    k_mlp_mfma<<<dim3(NBLK), dim3(256), 0, stream>>>(bbxyz, featT, wswz, nxf, idx, ymax, part);
    k_red<<<dim3(128), dim3(256), 0, stream>>>(part, p2);
    k_stats<<<dim3(1), dim3(256), 0, stream>>>(p2, gml, bml, ab);
    k_final<<<dim3(BP * COUT / 1024), dim3(256), 0, stream>>>(ymax, ab, out);
}

// Round 2
// 158.310 us; speedup vs baseline: 1.0885x; 1.0735x over previous
//
#include <hip/hip_runtime.h>
#include <math.h>

namespace {
constexpr int B    = 4;
constexpr int N    = 8192;
constexpr int P    = 2048;
constexpr int C    = 128;
constexpr int COUT = 256;
constexpr int NS   = 32;
constexpr int BP   = B * P;     // 8192
constexpr int BPB  = 2;         // bp per group (4 m-tiles -> acc[4][4] = 64 VGPRs)
constexpr int GRP  = 8;         // groups per block
constexpr int NBLK = BP / (BPB * GRP); // 512 blocks (2/CU)

// ---- workspace layout (bytes, all 256-aligned) ----
constexpr size_t OFF_FEATT = 0;                          // B*N*C bf16    = 8388608
constexpr size_t OFF_WSWZ  = 8388608;                    // 40960 bf16    = 81920
constexpr size_t OFF_SSLOT = 8470528;                    // 8*6 f64       = 384 (pad 512)
constexpr size_t OFF_SUMS  = 8471040;                    // 512 f32       = 2048 (pad 4096)
constexpr size_t OFF_NXF   = 8475136;                    // 8192*3 f32    = 98304
constexpr size_t OFF_IDX   = 8573440;                    // 8192*32 i32   = 1048576
constexpr size_t OFF_YMAX  = 9622016;                    // 8192*256 f32  = 8388608
constexpr size_t WS_NEED   = 18010624;                   // ~17.2 MB
} // namespace

typedef short bf16x8 __attribute__((ext_vector_type(8)));
typedef float f32x4  __attribute__((ext_vector_type(4)));

typedef const __attribute__((address_space(1))) void gas_void;
typedef __attribute__((address_space(3))) void las_void;
#define GLOBAL_LOAD_LDS16(gp, lp) \
    __builtin_amdgcn_global_load_lds((gas_void*)(gp), (las_void*)(lp), 16, 0, 0)

__device__ inline unsigned short f2bf(float f) {
    unsigned u = __float_as_uint(f);
    unsigned r = u + 0x7fffu + ((u >> 16) & 1u);
    return (unsigned short)(r >> 16);
}

// ---------------- K_A: shift BN partial stats (8 blocks, distinct slots) + zero sums ----
// R7: fused-pipeline restructure (8 kernels -> 4). Shift's conv is recomputed
// per-query inside k_front; only the grid-wide BN statistics need a prior
// dispatch. 8 blocks x 1024 pts each -> sslot[blk][6] (s0..2, sq0..2), fp64,
// deterministic tree. Block 8 zeroes the 512-float mlp-BN atomic sum buffer
// (poisoned workspace each call; same-stream dispatch order makes zeros
// visible to k_mlp's atomics).
__global__ __launch_bounds__(256) void k_prep(const float* __restrict__ ffps,
                                              const float* __restrict__ wsh,
                                              double* __restrict__ sslot,
                                              float* __restrict__ sums) {
#pragma clang fp contract(off)
    int blk = blockIdx.x, t = threadIdx.x;
    if (blk == 8) {
        ((f32x4*)sums)[t & 127] = (f32x4){0.f, 0.f, 0.f, 0.f};  // 128 x 16B = 512 f32
        return;
    }
    __shared__ double red[6][256];
    double w[9];
#pragma unroll
    for (int i = 0; i < 9; i++) w[i] = (double)wsh[i];
    double s[3] = {0, 0, 0}, sq[3] = {0, 0, 0};
#pragma unroll
    for (int i = 0; i < 4; i++) {
        int p = blk * 1024 + t + 256 * i;
        double f0 = (double)ffps[p * 3 + 0];
        double f1 = (double)ffps[p * 3 + 1];
        double f2 = (double)ffps[p * 3 + 2];
#pragma unroll
        for (int o = 0; o < 3; o++) {
            double xo = (w[o * 3 + 0] * f0 + w[o * 3 + 1] * f1) + w[o * 3 + 2] * f2;
            s[o] += xo;
            sq[o] += xo * xo;
        }
    }
#pragma unroll
    for (int o = 0; o < 3; o++) { red[o][t] = s[o]; red[3 + o][t] = sq[o]; }
    for (int off = 128; off > 0; off >>= 1) {
        __syncthreads();
        if (t < off) {
#pragma unroll
            for (int j = 0; j < 6; j++) red[j][t] += red[j][t + off];
        }
    }
    __syncthreads();
    if (t < 6) sslot[blk * 6 + t] = red[t][0];
}

// ---------------- K_B: fused front — ballq (2048 blks) || transpose (2048) || wswz (160) --
// Ballq blocks go first in index space (start immediately, own the long tail);
// transpose/wswz blocks backfill CUs as ballq's fast waves retire, overlapping
// what used to be 3 serialized dispatches. Ballq preamble reduces the 8 stat
// slots (48 f64 reads), recomputes the per-query conv+BN+ReLU in fp64
// (bit-identical math to the old k_shift: pow2 mean divide = exact multiply),
// writes nxf, then runs the unchanged R6 depth-2-pipelined scan.
__global__ __launch_bounds__(256) void k_front(const float* __restrict__ ffps,
                                               const float* __restrict__ bbxyz,
                                               const float* __restrict__ feat,
                                               const float* __restrict__ wsh,
                                               const float* __restrict__ gsh,
                                               const float* __restrict__ bsh,
                                               const float* __restrict__ wml,
                                               const double* __restrict__ sslot,
                                               unsigned short* __restrict__ featT,
                                               unsigned short* __restrict__ wswz,
                                               float* __restrict__ nxf,
                                               int* __restrict__ idxo) {
#pragma clang fp contract(off)
    int blk = blockIdx.x, t = threadIdx.x;
    if (blk >= 2048) {
        int rb = blk - 2048;
        if (rb < 2048) {
            // ---- transpose role: feat (B,C,N) f32 -> featT (B,N,C) bf16 ----
            __shared__ float tile[64][33];
            int tx = t & 31, ty = t >> 5;
            int n0 = (rb & 255) * 32, c0 = ((rb >> 8) & 1) * 64, b = rb >> 9;
            const float* src = feat + ((size_t)b * C + c0) * N + n0;
#pragma unroll
            for (int j = 0; j < 8; j++) tile[ty + 8 * j][tx] = src[(size_t)(ty + 8 * j) * N + tx];
            __syncthreads();
            int n = t >> 3;
            int k8 = (t & 7) * 8;
            unsigned vv[4];
#pragma unroll
            for (int i = 0; i < 4; i++) {
                unsigned lo = f2bf(tile[k8 + 2 * i][n]);
                unsigned hi = f2bf(tile[k8 + 2 * i + 1][n]);
                vv[i] = lo | (hi << 16);
            }
            *(int4*)&featT[((size_t)b * N + n0 + n) * C + c0 + k8] =
                make_int4((int)vv[0], (int)vv[1], (int)vv[2], (int)vv[3]);
        } else {
            // ---- wswz role: swizzle w_mlp into MFMA B-fragment order ----
            // wswz[rt(16)][ks(5)][lane(64)][j(8)]; element = W[rt*16+(lane&15)][k'];
            // k' = ks*32+(lane>>4)*8+j; k 0..127 -> col 3+k (feats); 128..130 -> col 0..2.
            int i = (rb - 2048) * 256 + t;             // < 40960
            int j = i & 7;
            int lane = (i >> 3) & 63;
            int rest = i >> 9;
            int ks = rest % 5, rt = rest / 5;
            int cout = rt * 16 + (lane & 15);
            int k = ks * 32 + (lane >> 4) * 8 + j;
            float v = 0.f;
            if (k < 128) v = wml[cout * 131 + 3 + k];
            else if (k < 131) v = wml[cout * 131 + (k - 128)];
            wswz[i] = f2bf(v);
        }
        return;
    }

    // ---- ballq role ----
    __shared__ double spar[6];
    if (t < 6) {
        double a = 0.0;
        for (int r = 0; r < 8; r++) a += sslot[r * 6 + t];
        spar[t] = a;
    }
    __syncthreads();
    int wv = t >> 6, lane = t & 63;
    int q = blk * 4 + wv;                          // bp index
    int b = q >> 11;                               // P = 2048
    double f0 = (double)ffps[q * 3 + 0];
    double f1 = (double)ffps[q * 3 + 1];
    double f2 = (double)ffps[q * 3 + 2];
    double qd[3];
#pragma unroll
    for (int o = 0; o < 3; o++) {
        double m  = spar[o] * (1.0 / 8192.0);      // pow2: exact, == /BP
        double v  = spar[3 + o] * (1.0 / 8192.0) - m * m;
        double is = 1.0 / sqrt(v + 1e-5);
        double x  = ((double)wsh[o * 3 + 0] * f0 + (double)wsh[o * 3 + 1] * f1) +
                    (double)wsh[o * 3 + 2] * f2;
        double y  = ((x - m) * is) * (double)gsh[o] + (double)bsh[o];
        qd[o] = (y > 0.0) ? y : 0.0;
    }
    double qx = qd[0], qy = qd[1], qz = qd[2];
    if (lane == 0) {
        nxf[q * 3 + 0] = (float)qx;
        nxf[q * 3 + 1] = (float)qy;
        nxf[q * 3 + 2] = (float)qz;
    }
    const double R2 = 0.8 * 0.8;
    // early-out: ball cannot intersect backbone cube [-1,1]^3 -> zero neighbors,
    // reference pads with index 0 in that case.
    {
        double ex = fmax(fmax(qx - 1.0, -1.0 - qx), 0.0);
        double ey = fmax(fmax(qy - 1.0, -1.0 - qy), 0.0);
        double ez = fmax(fmax(qz - 1.0, -1.0 - qz), 0.0);
        if (ex * ex + ey * ey + ez * ez >= R2) {
            if (lane < NS) idxo[q * NS + lane] = 0;
            return;
        }
    }
    const float* base = bbxyz + (size_t)b * N * 3;
    int found = 0, firstn = -1;

    float X0[8], Y0[8], Z0[8], X1[8], Y1[8], Z1[8], X2[8], Y2[8], Z2[8];

    auto loadb = [&](float (&XX)[8], float (&YY)[8], float (&ZZ)[8], int it) {
#pragma unroll
        for (int j = 0; j < 8; j++) {
            int n = it * 512 + j * 64 + lane;
            XX[j] = base[n * 3 + 0];
            YY[j] = base[n * 3 + 1];
            ZZ[j] = base[n * 3 + 2];
        }
    };
    auto proc = [&](float (&XX)[8], float (&YY)[8], float (&ZZ)[8], int it) {
#pragma clang fp contract(off)
#pragma unroll
        for (int j = 0; j < 8; j++) {
            int n = it * 512 + j * 64 + lane;
            double dx = qx - (double)XX[j];
            double dy = qy - (double)YY[j];
            double dz = qz - (double)ZZ[j];
            double d2 = (dx * dx + dy * dy) + dz * dz;
            bool within = d2 < R2;
            unsigned long long mask = __ballot(within);
            if (firstn < 0 && mask != 0ull) firstn = (n - lane) + (__ffsll(mask) - 1);
            if (within) {
                int rank = found + __popcll(mask & ((1ull << lane) - 1ull));
                if (rank < NS) idxo[q * NS + rank] = n;
            }
            found += __popcll(mask);
        }
    };

    loadb(X0, Y0, Z0, 0);
    loadb(X1, Y1, Z1, 1);
    loadb(X2, Y2, Z2, 2);

    for (int itb = 0; itb < 16; itb += 3) {        // iterations of 512 pts; N/512 = 16
        proc(X0, Y0, Z0, itb);
        if (found >= NS) break;
        loadb(X0, Y0, Z0, (itb + 3 < 16) ? itb + 3 : 0);
        if (itb + 1 >= 16) break;
        proc(X1, Y1, Z1, itb + 1);
        if (found >= NS) break;
        loadb(X1, Y1, Z1, (itb + 4 < 16) ? itb + 4 : 0);
        if (itb + 2 >= 16) break;
        proc(X2, Y2, Z2, itb + 2);
        if (found >= NS) break;
        loadb(X2, Y2, Z2, (itb + 5 < 16) ? itb + 5 : 0);
    }
    if (found < NS) {
        int padv = (found == 0) ? 0 : firstn;
        if (lane >= found && lane < NS) idxo[q * NS + lane] = padv;
    }
}

// ---------------- K_C: MFMA grouped 1x1 conv, pipelined, register-budgeted ----------
// 512 blocks x 8 groups x 2 bp. A = G (m=samples), B = W^T (n=couts). W fragments
// (wreg[5][4], 80 VGPRs) loaded ONCE and live across all groups; acc[4][4] = 64
// VGPRs; total deliberate ~210 < 256 (launch_bounds(256,2)) -> no spill. Feats
// double-buffered via global_load_lds(16B); each wave stages m-tile mt==w.
// xyz enters as in-register ks=4 A-frag. Idx prefetch 2 groups deep.
// R7: per-channel sm/sq go straight to the 512-float sums buffer via atomicAdd
// (512 adds/address over kernel lifetime, no contention) -> k_red/k_stats gone.
__global__ __launch_bounds__(256, 2) void k_mlp_mfma(
        const float* __restrict__ bbxyz,
        const unsigned short* __restrict__ featT,
        const unsigned short* __restrict__ wswz,
        const float* __restrict__ nxf,
        const int* __restrict__ idx,
        float* __restrict__ ymax,
        float* __restrict__ sums) {
    // G[buf][(mt*4+ks)*64 + lane][8]: element (s = mt*16+(lane&15), k' = ks*32+(lane>>4)*8+j)
    __shared__ alignas(16) unsigned short G[2][4 * 4 * 64 * 8];   // 2 x 16384 B
    int t = threadIdx.x, lane = t & 63, w = t >> 6;
    int q = lane >> 4, c16 = lane & 15;
    int blk = blockIdx.x;
    int bpbase = blk * (BPB * GRP);                // 16 bp per block
    const bf16x8* wp = (const bf16x8*)wswz;

    // ---- W fragments resident in registers for the whole kernel ----
    bf16x8 wreg[5][4];
#pragma unroll
    for (int ks = 0; ks < 5; ks++)
#pragma unroll
        for (int nt = 0; nt < 4; nt++)
            wreg[ks][nt] = wp[((w * 4 + nt) * 5 + ks) * 64 + lane];

    int n_cur[4], n_nxt[4], n_nx2[4];
#pragma unroll
    for (int mt = 0; mt < 4; mt++)
        n_cur[mt] = idx[(bpbase + (mt >> 1)) * NS + (mt & 1) * 16 + c16];
#pragma unroll
    for (int mt = 0; mt < 4; mt++)
        n_nxt[mt] = idx[(bpbase + BPB + (mt >> 1)) * NS + (mt & 1) * 16 + c16];
    {   // stage group 0: wave w stages m-tile w
        int bp = bpbase + (w >> 1);
        const unsigned short* row = featT + ((size_t)(bp >> 11) * N + n_cur[w]) * C + q * 8;
#pragma unroll
        for (int ks = 0; ks < 4; ks++)
            GLOBAL_LOAD_LDS16(row + ks * 32, &G[0][(w * 4 + ks) * 512]);
    }

    float smA[4] = {0.f, 0.f, 0.f, 0.f}, sqA[4] = {0.f, 0.f, 0.f, 0.f};

    for (int g = 0; g < GRP; g++) {
        int buf = g & 1;
        int bp0 = bpbase + g * BPB;
        if (g + 2 < GRP) {
#pragma unroll
            for (int mt = 0; mt < 4; mt++)
                n_nx2[mt] = idx[(bp0 + 2 * BPB + (mt >> 1)) * NS + (mt & 1) * 16 + c16];
        }
        __syncthreads();   // stage(g) drained; compute(g-1) reads of buf^1 done
        if (g + 1 < GRP) {
            int bp = bp0 + BPB + (w >> 1);
            const unsigned short* row = featT + ((size_t)(bp >> 11) * N + n_nxt[w]) * C + q * 8;
#pragma unroll
            for (int ks = 0; ks < 4; ks++)
                GLOBAL_LOAD_LDS16(row + ks * 32, &G[buf ^ 1][(w * 4 + ks) * 512]);
        }

        // ---- compute(g) on G[buf] ----
        f32x4 acc[4][4];
#pragma unroll
        for (int mt = 0; mt < 4; mt++)
#pragma unroll
            for (int nt = 0; nt < 4; nt++) acc[mt][nt] = (f32x4){0.f, 0.f, 0.f, 0.f};

#pragma unroll
        for (int ks = 0; ks < 4; ks++) {
            bf16x8 ag[4];
#pragma unroll
            for (int mt = 0; mt < 4; mt++)
                ag[mt] = *(const bf16x8*)&G[buf][((mt * 4 + ks) * 64 + lane) * 8];
#pragma unroll
            for (int nt = 0; nt < 4; nt++)
#pragma unroll
                for (int mt = 0; mt < 4; mt++)
                    acc[mt][nt] = __builtin_amdgcn_mfma_f32_16x16x32_bf16(ag[mt], wreg[ks][nt], acc[mt][nt], 0, 0, 0);
        }
        {   // ks = 4: xyz A-frags in registers (q==0: j0..2 = recentered xyz, else 0)
            bf16x8 agx[4];
#pragma unroll
            for (int mt = 0; mt < 4; mt++) {
                int bp = bp0 + (mt >> 1);
                unsigned u01 = 0, u23 = 0;
                if (q == 0) {
                    const float* src = bbxyz + ((size_t)(bp >> 11) * N + n_cur[mt]) * 3;
                    const float* ctr = nxf + bp * 3;
                    u01 = (unsigned)f2bf(src[0] - ctr[0]) | ((unsigned)f2bf(src[1] - ctr[1]) << 16);
                    u23 = (unsigned)f2bf(src[2] - ctr[2]);
                }
                union { int4 i; bf16x8 h; } u;
                u.i = make_int4((int)u01, (int)u23, 0, 0);
                agx[mt] = u.h;
            }
#pragma unroll
            for (int nt = 0; nt < 4; nt++)
#pragma unroll
                for (int mt = 0; mt < 4; mt++)
                    acc[mt][nt] = __builtin_amdgcn_mfma_f32_16x16x32_bf16(agx[mt], wreg[4][nt], acc[mt][nt], 0, 0, 0);
        }

        // ---- epilogue: max over 32 samples (2 m-tiles) per bp; sums accumulate ----
#pragma unroll
        for (int pm = 0; pm < BPB; pm++) {
            int bp = bp0 + pm;
#pragma unroll
            for (int nt = 0; nt < 4; nt++) {
                f32x4 a = acc[2 * pm][nt], c = acc[2 * pm + 1][nt];
                float mx = fmaxf(fmaxf(fmaxf(a[0], a[1]), fmaxf(a[2], a[3])),
                                 fmaxf(fmaxf(c[0], c[1]), fmaxf(c[2], c[3])));
                smA[nt] += ((a[0] + a[1]) + (a[2] + a[3])) + ((c[0] + c[1]) + (c[2] + c[3]));
                sqA[nt] += ((a[0] * a[0] + a[1] * a[1]) + (a[2] * a[2] + a[3] * a[3])) +
                           ((c[0] * c[0] + c[1] * c[1]) + (c[2] * c[2] + c[3] * c[3]));
                mx = fmaxf(mx, __shfl_xor(mx, 16, 64));
                mx = fmaxf(mx, __shfl_xor(mx, 32, 64));
                if (q == 0)
                    ymax[(size_t)bp * COUT + w * 64 + nt * 16 + c16] = mx;
            }
        }
#pragma unroll
        for (int mt = 0; mt < 4; mt++) { n_cur[mt] = n_nxt[mt]; n_nxt[mt] = n_nx2[mt]; }
    }

    // ---- per-channel sums -> global atomics (once per block) ----
#pragma unroll
    for (int nt = 0; nt < 4; nt++) {
        float sm = smA[nt], sq = sqA[nt];
        sm += __shfl_xor(sm, 16, 64);
        sm += __shfl_xor(sm, 32, 64);
        sq += __shfl_xor(sq, 16, 64);
        sq += __shfl_xor(sq, 32, 64);
        if (q == 0) {
            int cout = w * 64 + nt * 16 + c16;
            atomicAdd(&sums[cout], sm);
            atomicAdd(&sums[256 + cout], sq);
        }
    }
}

// ---------------- K_D: per-block BN params from sums, then relu(a*ymax+b), float4 ----
// R7: stats folded in. Thread t computes channel t's a/b once into LDS (one fp64
// rsqrt per thread), then the unchanged float4 apply. Pow2 count divide = exact
// multiply; matches old k_stats fp64 math.
__global__ __launch_bounds__(256) void k_final(const float* __restrict__ ymax,
                                               const float* __restrict__ sums,
                                               const float* __restrict__ gam,
                                               const float* __restrict__ bet,
                                               float* __restrict__ out) {
    __shared__ float sa[256], sb[256];
    int t = threadIdx.x;
    {
        double sm = (double)sums[t], sq = (double)sums[256 + t];
        double mean = sm * (1.0 / 262144.0);       // BP*NS, pow2
        double var = sq * (1.0 / 262144.0) - mean * mean;
        double a = (double)gam[t] / sqrt(var + 1e-5);
        sa[t] = (float)a;
        sb[t] = (float)((double)bet[t] - mean * a);
    }
    __syncthreads();
    int i = blockIdx.x * 256 + t;                  // float4 index, < BP*COUT/4
    int c0 = (t & 63) * 4;                         // (i&63)==(t&63) since 256%64==0
    f32x4 y = *(const f32x4*)&ymax[(size_t)i * 4];
    f32x4 r;
#pragma unroll
    for (int j = 0; j < 4; j++) r[j] = fmaxf(sa[c0 + j] * y[j] + sb[c0 + j], 0.f);
    *(f32x4*)&out[(size_t)i * 4] = r;
}

extern "C" void kernel_launch(void* const* d_in, const int* in_sizes, int n_in,
                              void* d_out, int out_size, void* d_ws, size_t ws_size,
                              hipStream_t stream) {
    const float* ffps  = (const float*)d_in[0];
    const float* bbxyz = (const float*)d_in[1];
    const float* feat  = (const float*)d_in[2];
    const float* wsh   = (const float*)d_in[3];
    const float* gsh   = (const float*)d_in[4];
    const float* bsh   = (const float*)d_in[5];
    const float* wml   = (const float*)d_in[6];
    const float* gml   = (const float*)d_in[7];
    const float* bml   = (const float*)d_in[8];
    float* out = (float*)d_out;
    char* ws = (char*)d_ws;
    if (ws_size < WS_NEED) return;

    unsigned short* featT = (unsigned short*)(ws + OFF_FEATT);
    unsigned short* wswz  = (unsigned short*)(ws + OFF_WSWZ);
    double*         sslot = (double*)(ws + OFF_SSLOT);
    float*          sums  = (float*)(ws + OFF_SUMS);
    float*          nxf   = (float*)(ws + OFF_NXF);
    int*            idx   = (int*)(ws + OFF_IDX);
    float*          ymax  = (float*)(ws + OFF_YMAX);

    k_prep<<<dim3(9), dim3(256), 0, stream>>>(ffps, wsh, sslot, sums);
    k_front<<<dim3(2048 + 2048 + 160), dim3(256), 0, stream>>>(
        ffps, bbxyz, feat, wsh, gsh, bsh, wml, sslot, featT, wswz, nxf, idx);
    k_mlp_mfma<<<dim3(NBLK), dim3(256), 0, stream>>>(bbxyz, featT, wswz, nxf, idx, ymax, sums);
    k_final<<<dim3(BP * COUT / 1024), dim3(256), 0, stream>>>(ymax, sums, gml, bml, out);
}

// Round 3
// 156.056 us; speedup vs baseline: 1.1043x; 1.0144x over previous
//
#include <hip/hip_runtime.h>
#include <math.h>

namespace {
constexpr int B    = 4;
constexpr int N    = 8192;
constexpr int P    = 2048;
constexpr int C    = 128;
constexpr int COUT = 256;
constexpr int NS   = 32;
constexpr int BP   = B * P;     // 8192
constexpr int BPB  = 2;         // bp per group (4 m-tiles -> acc[4][4] = 64 VGPRs)
constexpr int GRP  = 8;         // groups per block
constexpr int NBLK = BP / (BPB * GRP); // 512 blocks (2/CU)

// ---- workspace layout (bytes, all 256-aligned) ----
constexpr size_t OFF_FEATT = 0;                          // B*N*C bf16    = 8388608
constexpr size_t OFF_WSWZ  = 8388608;                    // 40960 bf16    = 81920
constexpr size_t OFF_SSLOT = 8470528;                    // 8*6 f64       = 384 (pad 512)
constexpr size_t OFF_SUMS  = 8471040;                    // 512 f32       = 2048 (pad 4096)
constexpr size_t OFF_IDX   = 8475136;                    // 8192*32 i32   = 1048576
constexpr size_t OFF_GX    = 9523712;                    // 8192*32 u64   = 2097152
constexpr size_t OFF_YMAX  = 11620864;                   // 8192*256 f32  = 8388608
constexpr size_t WS_NEED   = 20009472;                   // ~19.1 MB
} // namespace

typedef short bf16x8 __attribute__((ext_vector_type(8)));
typedef float f32x4  __attribute__((ext_vector_type(4)));

typedef const __attribute__((address_space(1))) void gas_void;
typedef __attribute__((address_space(3))) void las_void;
#define GLOBAL_LOAD_LDS16(gp, lp) \
    __builtin_amdgcn_global_load_lds((gas_void*)(gp), (las_void*)(lp), 16, 0, 0)

__device__ inline unsigned short f2bf(float f) {
    unsigned u = __float_as_uint(f);
    unsigned r = u + 0x7fffu + ((u >> 16) & 1u);
    return (unsigned short)(r >> 16);
}

// ---------------- K_A: shift BN partial stats (8 blocks, distinct slots) + zero sums ----
__global__ __launch_bounds__(256) void k_prep(const float* __restrict__ ffps,
                                              const float* __restrict__ wsh,
                                              double* __restrict__ sslot,
                                              float* __restrict__ sums) {
#pragma clang fp contract(off)
    int blk = blockIdx.x, t = threadIdx.x;
    if (blk == 8) {
        ((f32x4*)sums)[t & 127] = (f32x4){0.f, 0.f, 0.f, 0.f};  // 128 x 16B = 512 f32
        return;
    }
    __shared__ double red[6][256];
    double w[9];
#pragma unroll
    for (int i = 0; i < 9; i++) w[i] = (double)wsh[i];
    double s[3] = {0, 0, 0}, sq[3] = {0, 0, 0};
#pragma unroll
    for (int i = 0; i < 4; i++) {
        int p = blk * 1024 + t + 256 * i;
        double f0 = (double)ffps[p * 3 + 0];
        double f1 = (double)ffps[p * 3 + 1];
        double f2 = (double)ffps[p * 3 + 2];
#pragma unroll
        for (int o = 0; o < 3; o++) {
            double xo = (w[o * 3 + 0] * f0 + w[o * 3 + 1] * f1) + w[o * 3 + 2] * f2;
            s[o] += xo;
            sq[o] += xo * xo;
        }
    }
#pragma unroll
    for (int o = 0; o < 3; o++) { red[o][t] = s[o]; red[3 + o][t] = sq[o]; }
    for (int off = 128; off > 0; off >>= 1) {
        __syncthreads();
        if (t < off) {
#pragma unroll
            for (int j = 0; j < 6; j++) red[j][t] += red[j][t + off];
        }
    }
    __syncthreads();
    if (t < 6) sslot[blk * 6 + t] = red[t][0];
}

// ---------------- K_B: fused front — ballq (2048 blks) || transpose (2048) || wswz (160) --
// R8: ballq now also emits gxyz[bp][s] = packed-bf16 recentered xyz (uint2),
// computed as f32(backbone) - f32(center) -> f2bf — bit-identical to what
// k_mlp previously recomputed from idxo/bbxyz/nxf. nxf buffer deleted.
__global__ __launch_bounds__(256) void k_front(const float* __restrict__ ffps,
                                               const float* __restrict__ bbxyz,
                                               const float* __restrict__ feat,
                                               const float* __restrict__ wsh,
                                               const float* __restrict__ gsh,
                                               const float* __restrict__ bsh,
                                               const float* __restrict__ wml,
                                               const double* __restrict__ sslot,
                                               unsigned short* __restrict__ featT,
                                               unsigned short* __restrict__ wswz,
                                               int* __restrict__ idxo,
                                               uint2* __restrict__ gxo) {
#pragma clang fp contract(off)
    int blk = blockIdx.x, t = threadIdx.x;
    if (blk >= 2048) {
        int rb = blk - 2048;
        if (rb < 2048) {
            // ---- transpose role: feat (B,C,N) f32 -> featT (B,N,C) bf16 ----
            __shared__ float tile[64][33];
            int tx = t & 31, ty = t >> 5;
            int n0 = (rb & 255) * 32, c0 = ((rb >> 8) & 1) * 64, b = rb >> 9;
            const float* src = feat + ((size_t)b * C + c0) * N + n0;
#pragma unroll
            for (int j = 0; j < 8; j++) tile[ty + 8 * j][tx] = src[(size_t)(ty + 8 * j) * N + tx];
            __syncthreads();
            int n = t >> 3;
            int k8 = (t & 7) * 8;
            unsigned vv[4];
#pragma unroll
            for (int i = 0; i < 4; i++) {
                unsigned lo = f2bf(tile[k8 + 2 * i][n]);
                unsigned hi = f2bf(tile[k8 + 2 * i + 1][n]);
                vv[i] = lo | (hi << 16);
            }
            *(int4*)&featT[((size_t)b * N + n0 + n) * C + c0 + k8] =
                make_int4((int)vv[0], (int)vv[1], (int)vv[2], (int)vv[3]);
        } else {
            // ---- wswz role: swizzle w_mlp into MFMA B-fragment order ----
            int i = (rb - 2048) * 256 + t;             // < 40960
            int j = i & 7;
            int lane = (i >> 3) & 63;
            int rest = i >> 9;
            int ks = rest % 5, rt = rest / 5;
            int cout = rt * 16 + (lane & 15);
            int k = ks * 32 + (lane >> 4) * 8 + j;
            float v = 0.f;
            if (k < 128) v = wml[cout * 131 + 3 + k];
            else if (k < 131) v = wml[cout * 131 + (k - 128)];
            wswz[i] = f2bf(v);
        }
        return;
    }

    // ---- ballq role ----
    __shared__ double spar[6];
    if (t < 6) {
        double a = 0.0;
        for (int r = 0; r < 8; r++) a += sslot[r * 6 + t];
        spar[t] = a;
    }
    __syncthreads();
    int wv = t >> 6, lane = t & 63;
    int q = blk * 4 + wv;                          // bp index
    int b = q >> 11;                               // P = 2048
    double f0 = (double)ffps[q * 3 + 0];
    double f1 = (double)ffps[q * 3 + 1];
    double f2 = (double)ffps[q * 3 + 2];
    double qd[3];
#pragma unroll
    for (int o = 0; o < 3; o++) {
        double m  = spar[o] * (1.0 / 8192.0);      // pow2: exact, == /BP
        double v  = spar[3 + o] * (1.0 / 8192.0) - m * m;
        double is = 1.0 / sqrt(v + 1e-5);
        double x  = ((double)wsh[o * 3 + 0] * f0 + (double)wsh[o * 3 + 1] * f1) +
                    (double)wsh[o * 3 + 2] * f2;
        double y  = ((x - m) * is) * (double)gsh[o] + (double)bsh[o];
        qd[o] = (y > 0.0) ? y : 0.0;
    }
    double qx = qd[0], qy = qd[1], qz = qd[2];
    float cfx = (float)qx, cfy = (float)qy, cfz = (float)qz;  // == old nxf values
    const float* base = bbxyz + (size_t)b * N * 3;
    const double R2 = 0.8 * 0.8;
    // early-out: ball cannot intersect backbone cube [-1,1]^3 -> zero neighbors,
    // reference pads with index 0 in that case.
    {
        double ex = fmax(fmax(qx - 1.0, -1.0 - qx), 0.0);
        double ey = fmax(fmax(qy - 1.0, -1.0 - qy), 0.0);
        double ez = fmax(fmax(qz - 1.0, -1.0 - qz), 0.0);
        if (ex * ex + ey * ey + ez * ez >= R2) {
            if (lane < NS) {
                idxo[q * NS + lane] = 0;
                float rx = base[0] - cfx, ry = base[1] - cfy, rz = base[2] - cfz;
                unsigned u01 = (unsigned)f2bf(rx) | ((unsigned)f2bf(ry) << 16);
                gxo[q * NS + lane] = make_uint2(u01, (unsigned)f2bf(rz));
            }
            return;
        }
    }
    int found = 0, firstn = -1;

    float X0[8], Y0[8], Z0[8], X1[8], Y1[8], Z1[8], X2[8], Y2[8], Z2[8];

    auto loadb = [&](float (&XX)[8], float (&YY)[8], float (&ZZ)[8], int it) {
#pragma unroll
        for (int j = 0; j < 8; j++) {
            int n = it * 512 + j * 64 + lane;
            XX[j] = base[n * 3 + 0];
            YY[j] = base[n * 3 + 1];
            ZZ[j] = base[n * 3 + 2];
        }
    };
    auto proc = [&](float (&XX)[8], float (&YY)[8], float (&ZZ)[8], int it) {
#pragma clang fp contract(off)
#pragma unroll
        for (int j = 0; j < 8; j++) {
            int n = it * 512 + j * 64 + lane;
            double dx = qx - (double)XX[j];
            double dy = qy - (double)YY[j];
            double dz = qz - (double)ZZ[j];
            double d2 = (dx * dx + dy * dy) + dz * dz;
            bool within = d2 < R2;
            unsigned long long mask = __ballot(within);
            if (firstn < 0 && mask != 0ull) firstn = (n - lane) + (__ffsll(mask) - 1);
            if (within) {
                int rank = found + __popcll(mask & ((1ull << lane) - 1ull));
                if (rank < NS) {
                    idxo[q * NS + rank] = n;
                    float rx = XX[j] - cfx, ry = YY[j] - cfy, rz = ZZ[j] - cfz;
                    unsigned u01 = (unsigned)f2bf(rx) | ((unsigned)f2bf(ry) << 16);
                    gxo[q * NS + rank] = make_uint2(u01, (unsigned)f2bf(rz));
                }
            }
            found += __popcll(mask);
        }
    };

    loadb(X0, Y0, Z0, 0);
    loadb(X1, Y1, Z1, 1);
    loadb(X2, Y2, Z2, 2);

    for (int itb = 0; itb < 16; itb += 3) {        // iterations of 512 pts; N/512 = 16
        proc(X0, Y0, Z0, itb);
        if (found >= NS) break;
        loadb(X0, Y0, Z0, (itb + 3 < 16) ? itb + 3 : 0);
        if (itb + 1 >= 16) break;
        proc(X1, Y1, Z1, itb + 1);
        if (found >= NS) break;
        loadb(X1, Y1, Z1, (itb + 4 < 16) ? itb + 4 : 0);
        if (itb + 2 >= 16) break;
        proc(X2, Y2, Z2, itb + 2);
        if (found >= NS) break;
        loadb(X2, Y2, Z2, (itb + 5 < 16) ? itb + 5 : 0);
    }
    if (found < NS) {
        int padv = (found == 0) ? 0 : firstn;
        if (lane >= found && lane < NS) {
            idxo[q * NS + lane] = padv;
            float rx = base[padv * 3 + 0] - cfx;
            float ry = base[padv * 3 + 1] - cfy;
            float rz = base[padv * 3 + 2] - cfz;
            unsigned u01 = (unsigned)f2bf(rx) | ((unsigned)f2bf(ry) << 16);
            gxo[q * NS + lane] = make_uint2(u01, (unsigned)f2bf(rz));
        }
    }
}

// ---------------- K_C: MFMA grouped 1x1 conv, latency-clean pipeline ----------
// R8 fix of the two per-group exposed-latency windows found in R7 counters
// (MfmaUtil 16%): (1) idx prefetch was issued immediately BEFORE __syncthreads
// -> drained hot at the barrier every group; now all register prefetches are
// issued right AFTER the barrier so they drain one full compute phase later.
// (2) the ks=4 xyz gather (bbxyz+nxf, scattered, consumed immediately) is gone:
// ballq pre-packs gxyz; the A-frag is now one coalesced 8B load, prefetched a
// group ahead. Only the staging wave's own idx row is loaded (was 4x).
__global__ __launch_bounds__(256, 2) void k_mlp_mfma(
        const unsigned short* __restrict__ featT,
        const unsigned short* __restrict__ wswz,
        const int* __restrict__ idx,
        const uint2* __restrict__ gxyz,
        float* __restrict__ ymax,
        float* __restrict__ sums) {
    // G[buf][(mt*4+ks)*64 + lane][8]: element (s = mt*16+(lane&15), k' = ks*32+(lane>>4)*8+j)
    __shared__ alignas(16) unsigned short G[2][4 * 4 * 64 * 8];   // 2 x 16384 B
    int t = threadIdx.x, lane = t & 63, w = t >> 6;
    int q = lane >> 4, c16 = lane & 15;
    int blk = blockIdx.x;
    int bpbase = blk * (BPB * GRP);                // 16 bp per block
    const bf16x8* wp = (const bf16x8*)wswz;

    // ---- W fragments resident in registers for the whole kernel ----
    bf16x8 wreg[5][4];
#pragma unroll
    for (int ks = 0; ks < 5; ks++)
#pragma unroll
        for (int nt = 0; nt < 4; nt++)
            wreg[ks][nt] = wp[((w * 4 + nt) * 5 + ks) * 64 + lane];

    // staging row offset for wave w within a group: m-tile w
    int sOff = (w >> 1) * NS + (w & 1) * 16 + c16;
    size_t fb = (size_t)(bpbase >> 11) * N * C;    // batch base (16 | 2048: constant/block)

    int nS0 = idx[bpbase * NS + sOff];             // group 0 stage row
    int nS1 = idx[(bpbase + BPB) * NS + sOff];     // group 1 stage row
    uint2 gx_c[4] = {}, gx_n[4] = {};
    if (q == 0)
#pragma unroll
        for (int mt = 0; mt < 4; mt++)
            gx_c[mt] = gxyz[(bpbase + (mt >> 1)) * NS + (mt & 1) * 16 + c16];
    {   // stage group 0: wave w stages m-tile w
        const unsigned short* row = featT + fb + (size_t)nS0 * C + q * 8;
#pragma unroll
        for (int ks = 0; ks < 4; ks++)
            GLOBAL_LOAD_LDS16(row + ks * 32, &G[0][(w * 4 + ks) * 512]);
    }

    float smA[4] = {0.f, 0.f, 0.f, 0.f}, sqA[4] = {0.f, 0.f, 0.f, 0.f};

    for (int g = 0; g < GRP; g++) {
        int buf = g & 1;
        int bp0 = bpbase + g * BPB;
        __syncthreads();   // stage(g)+prefetch(g) drained; compute(g-1) reads of buf^1 done
        if (g + 1 < GRP) {
            const unsigned short* row = featT + fb + (size_t)nS1 * C + q * 8;
#pragma unroll
            for (int ks = 0; ks < 4; ks++)
                GLOBAL_LOAD_LDS16(row + ks * 32, &G[buf ^ 1][(w * 4 + ks) * 512]);
            if (q == 0)
#pragma unroll
                for (int mt = 0; mt < 4; mt++)
                    gx_n[mt] = gxyz[(bp0 + BPB + (mt >> 1)) * NS + (mt & 1) * 16 + c16];
        }
        if (g + 2 < GRP) nS0 = idx[(bp0 + 2 * BPB) * NS + sOff];   // row for group g+2

        // ---- compute(g) on G[buf] ----
        f32x4 acc[4][4];
#pragma unroll
        for (int mt = 0; mt < 4; mt++)
#pragma unroll
            for (int nt = 0; nt < 4; nt++) acc[mt][nt] = (f32x4){0.f, 0.f, 0.f, 0.f};

#pragma unroll
        for (int ks = 0; ks < 4; ks++) {
            bf16x8 ag[4];
#pragma unroll
            for (int mt = 0; mt < 4; mt++)
                ag[mt] = *(const bf16x8*)&G[buf][((mt * 4 + ks) * 64 + lane) * 8];
#pragma unroll
            for (int nt = 0; nt < 4; nt++)
#pragma unroll
                for (int mt = 0; mt < 4; mt++)
                    acc[mt][nt] = __builtin_amdgcn_mfma_f32_16x16x32_bf16(ag[mt], wreg[ks][nt], acc[mt][nt], 0, 0, 0);
        }
        {   // ks = 4: xyz A-frags from prefetched gxyz regs (q==0 lanes carry data)
            bf16x8 agx[4];
#pragma unroll
            for (int mt = 0; mt < 4; mt++) {
                union { int4 i; bf16x8 h; } u;
                u.i = make_int4(q == 0 ? (int)gx_c[mt].x : 0,
                                q == 0 ? (int)gx_c[mt].y : 0, 0, 0);
                agx[mt] = u.h;
            }
#pragma unroll
            for (int nt = 0; nt < 4; nt++)
#pragma unroll
                for (int mt = 0; mt < 4; mt++)
                    acc[mt][nt] = __builtin_amdgcn_mfma_f32_16x16x32_bf16(agx[mt], wreg[4][nt], acc[mt][nt], 0, 0, 0);
        }

        // ---- epilogue: max over 32 samples (2 m-tiles) per bp; sums accumulate ----
#pragma unroll
        for (int pm = 0; pm < BPB; pm++) {
            int bp = bp0 + pm;
#pragma unroll
            for (int nt = 0; nt < 4; nt++) {
                f32x4 a = acc[2 * pm][nt], c = acc[2 * pm + 1][nt];
                float mx = fmaxf(fmaxf(fmaxf(a[0], a[1]), fmaxf(a[2], a[3])),
                                 fmaxf(fmaxf(c[0], c[1]), fmaxf(c[2], c[3])));
                smA[nt] += ((a[0] + a[1]) + (a[2] + a[3])) + ((c[0] + c[1]) + (c[2] + c[3]));
                sqA[nt] += ((a[0] * a[0] + a[1] * a[1]) + (a[2] * a[2] + a[3] * a[3])) +
                           ((c[0] * c[0] + c[1] * c[1]) + (c[2] * c[2] + c[3] * c[3]));
                mx = fmaxf(mx, __shfl_xor(mx, 16, 64));
                mx = fmaxf(mx, __shfl_xor(mx, 32, 64));
                if (q == 0)
                    ymax[(size_t)bp * COUT + w * 64 + nt * 16 + c16] = mx;
            }
        }
        nS1 = nS0;                                 // rotate: g+2 row becomes "next"
#pragma unroll
        for (int mt = 0; mt < 4; mt++) gx_c[mt] = gx_n[mt];
    }

    // ---- per-channel sums -> global atomics (once per block) ----
#pragma unroll
    for (int nt = 0; nt < 4; nt++) {
        float sm = smA[nt], sq = sqA[nt];
        sm += __shfl_xor(sm, 16, 64);
        sm += __shfl_xor(sm, 32, 64);
        sq += __shfl_xor(sq, 16, 64);
        sq += __shfl_xor(sq, 32, 64);
        if (q == 0) {
            int cout = w * 64 + nt * 16 + c16;
            atomicAdd(&sums[cout], sm);
            atomicAdd(&sums[256 + cout], sq);
        }
    }
}

// ---------------- K_D: per-block BN params from sums, then relu(a*ymax+b), float4 ----
__global__ __launch_bounds__(256) void k_final(const float* __restrict__ ymax,
                                               const float* __restrict__ sums,
                                               const float* __restrict__ gam,
                                               const float* __restrict__ bet,
                                               float* __restrict__ out) {
    __shared__ float sa[256], sb[256];
    int t = threadIdx.x;
    {
        double sm = (double)sums[t], sq = (double)sums[256 + t];
        double mean = sm * (1.0 / 262144.0);       // BP*NS, pow2
        double var = sq * (1.0 / 262144.0) - mean * mean;
        double a = (double)gam[t] / sqrt(var + 1e-5);
        sa[t] = (float)a;
        sb[t] = (float)((double)bet[t] - mean * a);
    }
    __syncthreads();
    int i = blockIdx.x * 256 + t;                  // float4 index, < BP*COUT/4
    int c0 = (t & 63) * 4;                         // (i&63)==(t&63) since 256%64==0
    f32x4 y = *(const f32x4*)&ymax[(size_t)i * 4];
    f32x4 r;
#pragma unroll
    for (int j = 0; j < 4; j++) r[j] = fmaxf(sa[c0 + j] * y[j] + sb[c0 + j], 0.f);
    *(f32x4*)&out[(size_t)i * 4] = r;
}

extern "C" void kernel_launch(void* const* d_in, const int* in_sizes, int n_in,
                              void* d_out, int out_size, void* d_ws, size_t ws_size,
                              hipStream_t stream) {
    const float* ffps  = (const float*)d_in[0];
    const float* bbxyz = (const float*)d_in[1];
    const float* feat  = (const float*)d_in[2];
    const float* wsh   = (const float*)d_in[3];
    const float* gsh   = (const float*)d_in[4];
    const float* bsh   = (const float*)d_in[5];
    const float* wml   = (const float*)d_in[6];
    const float* gml   = (const float*)d_in[7];
    const float* bml   = (const float*)d_in[8];
    float* out = (float*)d_out;
    char* ws = (char*)d_ws;
    if (ws_size < WS_NEED) return;

    unsigned short* featT = (unsigned short*)(ws + OFF_FEATT);
    unsigned short* wswz  = (unsigned short*)(ws + OFF_WSWZ);
    double*         sslot = (double*)(ws + OFF_SSLOT);
    float*          sums  = (float*)(ws + OFF_SUMS);
    int*            idx   = (int*)(ws + OFF_IDX);
    uint2*          gx    = (uint2*)(ws + OFF_GX);
    float*          ymax  = (float*)(ws + OFF_YMAX);

    k_prep<<<dim3(9), dim3(256), 0, stream>>>(ffps, wsh, sslot, sums);
    k_front<<<dim3(2048 + 2048 + 160), dim3(256), 0, stream>>>(
        ffps, bbxyz, feat, wsh, gsh, bsh, wml, sslot, featT, wswz, idx, gx);
    k_mlp_mfma<<<dim3(NBLK), dim3(256), 0, stream>>>(featT, wswz, idx, gx, ymax, sums);
    k_final<<<dim3(BP * COUT / 1024), dim3(256), 0, stream>>>(ymax, sums, gml, bml, out);
}

// Round 4
// 155.455 us; speedup vs baseline: 1.1085x; 1.0039x over previous
//
#include <hip/hip_runtime.h>
#include <math.h>

namespace {
constexpr int B    = 4;
constexpr int N    = 8192;
constexpr int P    = 2048;
constexpr int C    = 128;
constexpr int COUT = 256;
constexpr int NS   = 32;
constexpr int BP   = B * P;     // 8192
constexpr int BPB  = 2;         // bp per group
constexpr int GRP  = 8;         // groups per block
constexpr int NBLK = (BP / (BPB * GRP)) * 2; // 1024 blocks (4/CU), n-split pairs

// ---- workspace layout (bytes, all 256-aligned) ----
constexpr size_t OFF_FEATT = 0;                          // B*N*C bf16    = 8388608
constexpr size_t OFF_WSWZ  = 8388608;                    // 40960 bf16    = 81920
constexpr size_t OFF_SSLOT = 8470528;                    // 8*6 f64       = 384 (pad 512)
constexpr size_t OFF_SUMS  = 8471040;                    // 512 f32       = 2048 (pad 4096)
constexpr size_t OFF_IDX   = 8475136;                    // 8192*32 i32   = 1048576
constexpr size_t OFF_GX    = 9523712;                    // 8192*32 u64   = 2097152
constexpr size_t OFF_YMAX  = 11620864;                   // 8192*256 f32  = 8388608
constexpr size_t WS_NEED   = 20009472;                   // ~19.1 MB
} // namespace

typedef short bf16x8 __attribute__((ext_vector_type(8)));
typedef float f32x4  __attribute__((ext_vector_type(4)));

typedef const __attribute__((address_space(1))) void gas_void;
typedef __attribute__((address_space(3))) void las_void;
#define GLOBAL_LOAD_LDS16(gp, lp) \
    __builtin_amdgcn_global_load_lds((gas_void*)(gp), (las_void*)(lp), 16, 0, 0)

__device__ inline unsigned short f2bf(float f) {
    unsigned u = __float_as_uint(f);
    unsigned r = u + 0x7fffu + ((u >> 16) & 1u);
    return (unsigned short)(r >> 16);
}

// ---------------- K_A: shift BN partial stats (8 blocks, distinct slots) + zero sums ----
__global__ __launch_bounds__(256) void k_prep(const float* __restrict__ ffps,
                                              const float* __restrict__ wsh,
                                              double* __restrict__ sslot,
                                              float* __restrict__ sums) {
#pragma clang fp contract(off)
    int blk = blockIdx.x, t = threadIdx.x;
    if (blk == 8) {
        ((f32x4*)sums)[t & 127] = (f32x4){0.f, 0.f, 0.f, 0.f};  // 128 x 16B = 512 f32
        return;
    }
    __shared__ double red[6][256];
    double w[9];
#pragma unroll
    for (int i = 0; i < 9; i++) w[i] = (double)wsh[i];
    double s[3] = {0, 0, 0}, sq[3] = {0, 0, 0};
#pragma unroll
    for (int i = 0; i < 4; i++) {
        int p = blk * 1024 + t + 256 * i;
        double f0 = (double)ffps[p * 3 + 0];
        double f1 = (double)ffps[p * 3 + 1];
        double f2 = (double)ffps[p * 3 + 2];
#pragma unroll
        for (int o = 0; o < 3; o++) {
            double xo = (w[o * 3 + 0] * f0 + w[o * 3 + 1] * f1) + w[o * 3 + 2] * f2;
            s[o] += xo;
            sq[o] += xo * xo;
        }
    }
#pragma unroll
    for (int o = 0; o < 3; o++) { red[o][t] = s[o]; red[3 + o][t] = sq[o]; }
    for (int off = 128; off > 0; off >>= 1) {
        __syncthreads();
        if (t < off) {
#pragma unroll
            for (int j = 0; j < 6; j++) red[j][t] += red[j][t + off];
        }
    }
    __syncthreads();
    if (t < 6) sslot[blk * 6 + t] = red[t][0];
}

// ---------------- K_B: fused front — ballq (2048 blks) || transpose (2048) || wswz (160) --
// R9: ballq distance test now runs in f32 with an f64 fallback only when
// |d2f - R2| < 1e-4 (f32 d2 abs error <= ~1.2e-6 incl. center rounding -> 80x
// margin; fallback replicates the exact original f64 op order) — selection is
// bit-identical, scan VALU cost ~2.5x lower.
__global__ __launch_bounds__(256) void k_front(const float* __restrict__ ffps,
                                               const float* __restrict__ bbxyz,
                                               const float* __restrict__ feat,
                                               const float* __restrict__ wsh,
                                               const float* __restrict__ gsh,
                                               const float* __restrict__ bsh,
                                               const float* __restrict__ wml,
                                               const double* __restrict__ sslot,
                                               unsigned short* __restrict__ featT,
                                               unsigned short* __restrict__ wswz,
                                               int* __restrict__ idxo,
                                               uint2* __restrict__ gxo) {
#pragma clang fp contract(off)
    int blk = blockIdx.x, t = threadIdx.x;
    if (blk >= 2048) {
        int rb = blk - 2048;
        if (rb < 2048) {
            // ---- transpose role: feat (B,C,N) f32 -> featT (B,N,C) bf16 ----
            __shared__ float tile[64][33];
            int tx = t & 31, ty = t >> 5;
            int n0 = (rb & 255) * 32, c0 = ((rb >> 8) & 1) * 64, b = rb >> 9;
            const float* src = feat + ((size_t)b * C + c0) * N + n0;
#pragma unroll
            for (int j = 0; j < 8; j++) tile[ty + 8 * j][tx] = src[(size_t)(ty + 8 * j) * N + tx];
            __syncthreads();
            int n = t >> 3;
            int k8 = (t & 7) * 8;
            unsigned vv[4];
#pragma unroll
            for (int i = 0; i < 4; i++) {
                unsigned lo = f2bf(tile[k8 + 2 * i][n]);
                unsigned hi = f2bf(tile[k8 + 2 * i + 1][n]);
                vv[i] = lo | (hi << 16);
            }
            *(int4*)&featT[((size_t)b * N + n0 + n) * C + c0 + k8] =
                make_int4((int)vv[0], (int)vv[1], (int)vv[2], (int)vv[3]);
        } else {
            // ---- wswz role: swizzle w_mlp into MFMA B-fragment order ----
            // wswz[rt(16)][ks(5)][lane(64)][j(8)]; element = W[rt*16+(lane&15)][k'];
            // k' = ks*32+(lane>>4)*8+j; k 0..127 -> col 3+k (feats); 128..130 -> col 0..2.
            int i = (rb - 2048) * 256 + t;             // < 40960
            int j = i & 7;
            int lane = (i >> 3) & 63;
            int rest = i >> 9;
            int ks = rest % 5, rt = rest / 5;
            int cout = rt * 16 + (lane & 15);
            int k = ks * 32 + (lane >> 4) * 8 + j;
            float v = 0.f;
            if (k < 128) v = wml[cout * 131 + 3 + k];
            else if (k < 131) v = wml[cout * 131 + (k - 128)];
            wswz[i] = f2bf(v);
        }
        return;
    }

    // ---- ballq role ----
    __shared__ double spar[6];
    if (t < 6) {
        double a = 0.0;
        for (int r = 0; r < 8; r++) a += sslot[r * 6 + t];
        spar[t] = a;
    }
    __syncthreads();
    int wv = t >> 6, lane = t & 63;
    int q = blk * 4 + wv;                          // bp index
    int b = q >> 11;                               // P = 2048
    double f0 = (double)ffps[q * 3 + 0];
    double f1 = (double)ffps[q * 3 + 1];
    double f2 = (double)ffps[q * 3 + 2];
    double qd[3];
#pragma unroll
    for (int o = 0; o < 3; o++) {
        double m  = spar[o] * (1.0 / 8192.0);      // pow2: exact, == /BP
        double v  = spar[3 + o] * (1.0 / 8192.0) - m * m;
        double is = 1.0 / sqrt(v + 1e-5);
        double x  = ((double)wsh[o * 3 + 0] * f0 + (double)wsh[o * 3 + 1] * f1) +
                    (double)wsh[o * 3 + 2] * f2;
        double y  = ((x - m) * is) * (double)gsh[o] + (double)bsh[o];
        qd[o] = (y > 0.0) ? y : 0.0;
    }
    double qx = qd[0], qy = qd[1], qz = qd[2];
    float cfx = (float)qx, cfy = (float)qy, cfz = (float)qz;
    const float* base = bbxyz + (size_t)b * N * 3;
    const double R2 = 0.8 * 0.8;
    const float R2F = 0.64f;
    // early-out: ball cannot intersect backbone cube [-1,1]^3 -> zero neighbors,
    // reference pads with index 0 in that case.
    {
        double ex = fmax(fmax(qx - 1.0, -1.0 - qx), 0.0);
        double ey = fmax(fmax(qy - 1.0, -1.0 - qy), 0.0);
        double ez = fmax(fmax(qz - 1.0, -1.0 - qz), 0.0);
        if (ex * ex + ey * ey + ez * ez >= R2) {
            if (lane < NS) {
                idxo[q * NS + lane] = 0;
                float rx = base[0] - cfx, ry = base[1] - cfy, rz = base[2] - cfz;
                unsigned u01 = (unsigned)f2bf(rx) | ((unsigned)f2bf(ry) << 16);
                gxo[q * NS + lane] = make_uint2(u01, (unsigned)f2bf(rz));
            }
            return;
        }
    }
    int found = 0, firstn = -1;

    float X0[8], Y0[8], Z0[8], X1[8], Y1[8], Z1[8], X2[8], Y2[8], Z2[8];

    auto loadb = [&](float (&XX)[8], float (&YY)[8], float (&ZZ)[8], int it) {
#pragma unroll
        for (int j = 0; j < 8; j++) {
            int n = it * 512 + j * 64 + lane;
            XX[j] = base[n * 3 + 0];
            YY[j] = base[n * 3 + 1];
            ZZ[j] = base[n * 3 + 2];
        }
    };
    auto proc = [&](float (&XX)[8], float (&YY)[8], float (&ZZ)[8], int it) {
#pragma clang fp contract(off)
#pragma unroll
        for (int j = 0; j < 8; j++) {
            int n = it * 512 + j * 64 + lane;
            float dxf = cfx - XX[j];
            float dyf = cfy - YY[j];
            float dzf = cfz - ZZ[j];
            float d2f = (dxf * dxf + dyf * dyf) + dzf * dzf;
            bool within;
            if (__builtin_expect(fabsf(d2f - R2F) < 1e-4f, 0)) {
                // borderline: exact original f64 op order decides
                double dx = qx - (double)XX[j];
                double dy = qy - (double)YY[j];
                double dz = qz - (double)ZZ[j];
                within = ((dx * dx + dy * dy) + dz * dz) < R2;
            } else {
                within = d2f < R2F;
            }
            unsigned long long mask = __ballot(within);
            if (firstn < 0 && mask != 0ull) firstn = (n - lane) + (__ffsll(mask) - 1);
            if (within) {
                int rank = found + __popcll(mask & ((1ull << lane) - 1ull));
                if (rank < NS) {
                    idxo[q * NS + rank] = n;
                    float rx = XX[j] - cfx, ry = YY[j] - cfy, rz = ZZ[j] - cfz;
                    unsigned u01 = (unsigned)f2bf(rx) | ((unsigned)f2bf(ry) << 16);
                    gxo[q * NS + rank] = make_uint2(u01, (unsigned)f2bf(rz));
                }
            }
            found += __popcll(mask);
        }
    };

    loadb(X0, Y0, Z0, 0);
    loadb(X1, Y1, Z1, 1);
    loadb(X2, Y2, Z2, 2);

    for (int itb = 0; itb < 16; itb += 3) {        // iterations of 512 pts; N/512 = 16
        proc(X0, Y0, Z0, itb);
        if (found >= NS) break;
        loadb(X0, Y0, Z0, (itb + 3 < 16) ? itb + 3 : 0);
        if (itb + 1 >= 16) break;
        proc(X1, Y1, Z1, itb + 1);
        if (found >= NS) break;
        loadb(X1, Y1, Z1, (itb + 4 < 16) ? itb + 4 : 0);
        if (itb + 2 >= 16) break;
        proc(X2, Y2, Z2, itb + 2);
        if (found >= NS) break;
        loadb(X2, Y2, Z2, (itb + 5 < 16) ? itb + 5 : 0);
    }
    if (found < NS) {
        int padv = (found == 0) ? 0 : firstn;
        if (lane >= found && lane < NS) {
            idxo[q * NS + lane] = padv;
            float rx = base[padv * 3 + 0] - cfx;
            float ry = base[padv * 3 + 1] - cfy;
            float rz = base[padv * 3 + 2] - cfz;
            unsigned u01 = (unsigned)f2bf(rx) | ((unsigned)f2bf(ry) << 16);
            gxo[q * NS + lane] = make_uint2(u01, (unsigned)f2bf(rz));
        }
    }
}

// ---------------- K_C: MFMA grouped 1x1 conv, n-split for 4 blocks/CU ----------
// R9: R8's issue-order fix moved k_mlp only 49->~42us; per-group wall ~13k cyc vs
// ~2.2k cyc of issue work => exposed gather latency with only 2 blocks/CU to
// overlap. Fix = occupancy: split couts across block PAIRS (blk&1 -> cout half),
// grid 512->1024 = 4 blocks/CU. Per-wave regs drop (wreg 80->40, acc 64->32) so
// launch_bounds(256,4) fits ~100 regs incl. AGPRs, no spill; LDS 4x32KB=128<=160.
// Staging (L2-resident issue work) doubles, latency hiding doubles. idx values
// clamped &(N-1): no-op for valid data, keeps rocprof replay-on-poison sane.
__global__ __launch_bounds__(256, 4) void k_mlp_mfma(
        const unsigned short* __restrict__ featT,
        const unsigned short* __restrict__ wswz,
        const int* __restrict__ idx,
        const uint2* __restrict__ gxyz,
        float* __restrict__ ymax,
        float* __restrict__ sums) {
    // G[buf][(mt*4+ks)*64 + lane][8]: element (s = mt*16+(lane&15), k' = ks*32+(lane>>4)*8+j)
    __shared__ alignas(16) unsigned short G[2][4 * 4 * 64 * 8];   // 2 x 16384 B
    int t = threadIdx.x, lane = t & 63, w = t >> 6;
    int q = lane >> 4, c16 = lane & 15;
    int blk = blockIdx.x;
    int nh = blk & 1;                              // cout half (0: 0..127, 1: 128..255)
    int bpbase = (blk >> 1) * (BPB * GRP);         // 16 bp per block pair
    const bf16x8* wp = (const bf16x8*)wswz;

    // ---- W fragments resident in registers: this wave's 2 n-tiles ----
    bf16x8 wreg[5][2];
#pragma unroll
    for (int ks = 0; ks < 5; ks++)
#pragma unroll
        for (int nt = 0; nt < 2; nt++)
            wreg[ks][nt] = wp[((nh * 8 + w * 2 + nt) * 5 + ks) * 64 + lane];

    // staging row offset for wave w within a group: m-tile w
    int sOff = (w >> 1) * NS + (w & 1) * 16 + c16;
    size_t fb = (size_t)(bpbase >> 11) * N * C;    // batch base (16 | 2048: constant/block)

    int nS0 = idx[bpbase * NS + sOff] & (N - 1);           // group 0 stage row
    int nS1 = idx[(bpbase + BPB) * NS + sOff] & (N - 1);   // group 1 stage row
    uint2 gx_c[4] = {}, gx_n[4] = {};
    if (q == 0)
#pragma unroll
        for (int mt = 0; mt < 4; mt++)
            gx_c[mt] = gxyz[(bpbase + (mt >> 1)) * NS + (mt & 1) * 16 + c16];
    {   // stage group 0: wave w stages m-tile w
        const unsigned short* row = featT + fb + (size_t)nS0 * C + q * 8;
#pragma unroll
        for (int ks = 0; ks < 4; ks++)
            GLOBAL_LOAD_LDS16(row + ks * 32, &G[0][(w * 4 + ks) * 512]);
    }

    float smA[2] = {0.f, 0.f}, sqA[2] = {0.f, 0.f};

    for (int g = 0; g < GRP; g++) {
        int buf = g & 1;
        int bp0 = bpbase + g * BPB;
        __syncthreads();   // stage(g)+prefetch(g) drained; compute(g-1) reads of buf^1 done
        if (g + 1 < GRP) {
            const unsigned short* row = featT + fb + (size_t)nS1 * C + q * 8;
#pragma unroll
            for (int ks = 0; ks < 4; ks++)
                GLOBAL_LOAD_LDS16(row + ks * 32, &G[buf ^ 1][(w * 4 + ks) * 512]);
            if (q == 0)
#pragma unroll
                for (int mt = 0; mt < 4; mt++)
                    gx_n[mt] = gxyz[(bp0 + BPB + (mt >> 1)) * NS + (mt & 1) * 16 + c16];
        }
        if (g + 2 < GRP) nS0 = idx[(bp0 + 2 * BPB) * NS + sOff] & (N - 1);

        // ---- compute(g) on G[buf] ----
        f32x4 acc[4][2];
#pragma unroll
        for (int mt = 0; mt < 4; mt++)
#pragma unroll
            for (int nt = 0; nt < 2; nt++) acc[mt][nt] = (f32x4){0.f, 0.f, 0.f, 0.f};

#pragma unroll
        for (int ks = 0; ks < 4; ks++) {
            bf16x8 ag[4];
#pragma unroll
            for (int mt = 0; mt < 4; mt++)
                ag[mt] = *(const bf16x8*)&G[buf][((mt * 4 + ks) * 64 + lane) * 8];
#pragma unroll
            for (int nt = 0; nt < 2; nt++)
#pragma unroll
                for (int mt = 0; mt < 4; mt++)
                    acc[mt][nt] = __builtin_amdgcn_mfma_f32_16x16x32_bf16(ag[mt], wreg[ks][nt], acc[mt][nt], 0, 0, 0);
        }
        {   // ks = 4: xyz A-frags from prefetched gxyz regs (q==0 lanes carry data)
            bf16x8 agx[4];
#pragma unroll
            for (int mt = 0; mt < 4; mt++) {
                union { int4 i; bf16x8 h; } u;
                u.i = make_int4(q == 0 ? (int)gx_c[mt].x : 0,
                                q == 0 ? (int)gx_c[mt].y : 0, 0, 0);
                agx[mt] = u.h;
            }
#pragma unroll
            for (int nt = 0; nt < 2; nt++)
#pragma unroll
                for (int mt = 0; mt < 4; mt++)
                    acc[mt][nt] = __builtin_amdgcn_mfma_f32_16x16x32_bf16(agx[mt], wreg[4][nt], acc[mt][nt], 0, 0, 0);
        }

        // ---- epilogue: max over 32 samples (2 m-tiles) per bp; sums accumulate ----
#pragma unroll
        for (int pm = 0; pm < BPB; pm++) {
            int bp = bp0 + pm;
#pragma unroll
            for (int nt = 0; nt < 2; nt++) {
                f32x4 a = acc[2 * pm][nt], c = acc[2 * pm + 1][nt];
                float mx = fmaxf(fmaxf(fmaxf(a[0], a[1]), fmaxf(a[2], a[3])),
                                 fmaxf(fmaxf(c[0], c[1]), fmaxf(c[2], c[3])));
                smA[nt] += ((a[0] + a[1]) + (a[2] + a[3])) + ((c[0] + c[1]) + (c[2] + c[3]));
                sqA[nt] += ((a[0] * a[0] + a[1] * a[1]) + (a[2] * a[2] + a[3] * a[3])) +
                           ((c[0] * c[0] + c[1] * c[1]) + (c[2] * c[2] + c[3] * c[3]));
                mx = fmaxf(mx, __shfl_xor(mx, 16, 64));
                mx = fmaxf(mx, __shfl_xor(mx, 32, 64));
                if (q == 0)
                    ymax[(size_t)bp * COUT + nh * 128 + w * 32 + nt * 16 + c16] = mx;
            }
        }
        nS1 = nS0;                                 // rotate: g+2 row becomes "next"
#pragma unroll
        for (int mt = 0; mt < 4; mt++) gx_c[mt] = gx_n[mt];
    }

    // ---- per-channel sums -> global atomics (once per block) ----
#pragma unroll
    for (int nt = 0; nt < 2; nt++) {
        float sm = smA[nt], sq = sqA[nt];
        sm += __shfl_xor(sm, 16, 64);
        sm += __shfl_xor(sm, 32, 64);
        sq += __shfl_xor(sq, 16, 64);
        sq += __shfl_xor(sq, 32, 64);
        if (q == 0) {
            int cout = nh * 128 + w * 32 + nt * 16 + c16;
            atomicAdd(&sums[cout], sm);
            atomicAdd(&sums[256 + cout], sq);
        }
    }
}

// ---------------- K_D: per-block BN params from sums, then relu(a*ymax+b), float4 ----
__global__ __launch_bounds__(256) void k_final(const float* __restrict__ ymax,
                                               const float* __restrict__ sums,
                                               const float* __restrict__ gam,
                                               const float* __restrict__ bet,
                                               float* __restrict__ out) {
    __shared__ float sa[256], sb[256];
    int t = threadIdx.x;
    {
        double sm = (double)sums[t], sq = (double)sums[256 + t];
        double mean = sm * (1.0 / 262144.0);       // BP*NS, pow2
        double var = sq * (1.0 / 262144.0) - mean * mean;
        double a = (double)gam[t] / sqrt(var + 1e-5);
        sa[t] = (float)a;
        sb[t] = (float)((double)bet[t] - mean * a);
    }
    __syncthreads();
    int i = blockIdx.x * 256 + t;                  // float4 index, < BP*COUT/4
    int c0 = (t & 63) * 4;                         // (i&63)==(t&63) since 256%64==0
    f32x4 y = *(const f32x4*)&ymax[(size_t)i * 4];
    f32x4 r;
#pragma unroll
    for (int j = 0; j < 4; j++) r[j] = fmaxf(sa[c0 + j] * y[j] + sb[c0 + j], 0.f);
    *(f32x4*)&out[(size_t)i * 4] = r;
}

extern "C" void kernel_launch(void* const* d_in, const int* in_sizes, int n_in,
                              void* d_out, int out_size, void* d_ws, size_t ws_size,
                              hipStream_t stream) {
    const float* ffps  = (const float*)d_in[0];
    const float* bbxyz = (const float*)d_in[1];
    const float* feat  = (const float*)d_in[2];
    const float* wsh   = (const float*)d_in[3];
    const float* gsh   = (const float*)d_in[4];
    const float* bsh   = (const float*)d_in[5];
    const float* wml   = (const float*)d_in[6];
    const float* gml   = (const float*)d_in[7];
    const float* bml   = (const float*)d_in[8];
    float* out = (float*)d_out;
    char* ws = (char*)d_ws;
    if (ws_size < WS_NEED) return;

    unsigned short* featT = (unsigned short*)(ws + OFF_FEATT);
    unsigned short* wswz  = (unsigned short*)(ws + OFF_WSWZ);
    double*         sslot = (double*)(ws + OFF_SSLOT);
    float*          sums  = (float*)(ws + OFF_SUMS);
    int*            idx   = (int*)(ws + OFF_IDX);
    uint2*          gx    = (uint2*)(ws + OFF_GX);
    float*          ymax  = (float*)(ws + OFF_YMAX);

    k_prep<<<dim3(9), dim3(256), 0, stream>>>(ffps, wsh, sslot, sums);
    k_front<<<dim3(2048 + 2048 + 160), dim3(256), 0, stream>>>(
        ffps, bbxyz, feat, wsh, gsh, bsh, wml, sslot, featT, wswz, idx, gx);
    k_mlp_mfma<<<dim3(NBLK), dim3(256), 0, stream>>>(featT, wswz, idx, gx, ymax, sums);
    k_final<<<dim3(BP * COUT / 1024), dim3(256), 0, stream>>>(ymax, sums, gml, bml, out);
}